// Round 11
// baseline (80.010 us; speedup 1.0000x reference)
//
#include <hip/hip_runtime.h>
#include <hip/hip_bf16.h>

// Problem constants
#define N_OUTP 16384
#define KNB    16
#define OUT_D  256

typedef __bf16 bf16x8_t __attribute__((ext_vector_type(8)));
typedef float  f32x4_t  __attribute__((ext_vector_type(4)));
typedef float  f32x2_t  __attribute__((ext_vector_type(2)));

__device__ __forceinline__ unsigned pk2(float a, float b) {
  __bf16 b0 = (__bf16)a, b1 = (__bf16)b;
  return ((unsigned)__builtin_bit_cast(unsigned short, b1) << 16) |
          (unsigned)__builtin_bit_cast(unsigned short, b0);
}
__device__ __forceinline__ float ulo(unsigned u) {
  return __builtin_bit_cast(float, u << 16);
}
__device__ __forceinline__ float uhi(unsigned u) {
  return __builtin_bit_cast(float, u & 0xffff0000u);
}

// ---------------------------------------------------------------------------
// pack_B: W_out (2048x256 f32) -> bf16 B-fragments (1 MB in ws).
// Chunk c=(kk,nt,lane): lane l holds B[kk*32+(l>>4)*8+j][nt*16+(l&15)].
// ---------------------------------------------------------------------------
__global__ __launch_bounds__(256) void pack_B_kernel(
    const float* __restrict__ W, uint4* __restrict__ Bws)
{
  __shared__ float wlds[32 * 260];
  const int kk = blockIdx.x;
  const int t  = threadIdx.x;

  const float4* Wb = (const float4*)(W + kk * 32 * OUT_D);
#pragma unroll
  for (int i = 0; i < 8; ++i) {
    int idx = i * 256 + t;
    int row = idx >> 6, c4 = idx & 63;
    float4 v = Wb[idx];
    *(float4*)(wlds + row * 260 + c4 * 4) = v;
  }
  __syncthreads();

#pragma unroll
  for (int j = 0; j < 4; ++j) {
    int c  = j * 256 + t;
    int l  = c & 63, nt = c >> 6;
    int r0 = (l >> 4) * 8, col = nt * 16 + (l & 15);
    union { unsigned short s[8]; uint4 v; } u;
#pragma unroll
    for (int jj = 0; jj < 8; ++jj) {
      __bf16 b = (__bf16)wlds[(r0 + jj) * 260 + col];
      u.s[jj] = __builtin_bit_cast(unsigned short, b);
    }
    Bws[(size_t)kk * 1024 + c] = u.v;
  }
}

// ---------------------------------------------------------------------------
// fused: per block of 32 output rows (512 blocks, 512 threads):
//   P0: gather x (bf16 -> LDS xpk) + weights (bf16 -> LDS wb)
//   P1: normalize wb in place (per (row,m), sum over k)
//   per m-chunk d (8 m = 512 k): einsum -> A-frag chunk in LDS; barrier;
//     MFMA (8 waves = 4 col-groups x K-parity halves), B from global/L2
//     with chunk-start + rolling prefetch; barrier.
//   Epilogue: half-0 parks cacc in LDS (xpk region reused); half-1 adds+stores.
// LDS layout (bytes):
//   xpk: [r 32][580 u32]   (row r8, k-stride 36 u32, 16B aligned)  74240
//   wb : [r 32][324 u32]   (k-stride 20 u32)                       41472
//   ac : 2048 uint4 A-frag chunk [mtile 2][kkl 16][lane 64]        32768
// ---------------------------------------------------------------------------
#define XPK_OFF 0
#define XPK_R   580
#define WB_OFF  74240
#define WB_R    324
#define AC_OFF  115712
#define LDS_TOT 148480

__global__ __launch_bounds__(512) void fused_kernel(
    const float* __restrict__ x,
    const float* __restrict__ d_dists,
    const float* __restrict__ d_phi,
    const float* __restrict__ dists,
    const float* __restrict__ sigma_p,
    const float* __restrict__ kappa_p,
    const float* __restrict__ phi,
    const uint4* __restrict__ Bws,
    const int*   __restrict__ nh_idx,
    float*       __restrict__ out)
{
  extern __shared__ char smem[];
  unsigned* xpk = (unsigned*)(smem + XPK_OFF);
  unsigned* wb  = (unsigned*)(smem + WB_OFF);
  uint4*    ac  = (uint4*)(smem + AC_OFF);

  const int t  = threadIdx.x;
  const int n0 = blockIdx.x * 32;

  // ---- P0a: issue gather (thread -> (gr = t>>4 row, gk = t&15 neighbor))
  const int gr = t >> 4, gk = t & 15;
  const int gidx = nh_idx[n0 * KNB + t];         // coalesced
  const float4* xr = (const float4*)x + (size_t)gidx * 16;
  float4 xreg[16];
#pragma unroll
  for (int j = 0; j < 16; ++j) xreg[j] = xr[j];

  // ---- P0b: weights (hidden under gather latency)
  {
    const float sinv = 1.0f / sigma_p[0];
    const float kap  = kappa_p[0];
    float phiv[8], distv[4];
#pragma unroll
    for (int p = 0; p < 8; ++p) phiv[p] = phi[p];
#pragma unroll
    for (int d = 0; d < 4; ++d) distv[d] = dists[d];

    float dd = d_dists[n0 * KNB + t];
    float dp = d_phi[n0 * KNB + t];
    float wp[8];
#pragma unroll
    for (int p = 0; p < 8; ++p) wp[p] = __expf(kap * __cosf(dp - phiv[p]));

    unsigned* wrow = wb + gr * WB_R + gk * 20;
#pragma unroll
    for (int d = 0; d < 4; ++d) {
      float td = (dd - distv[d]) * sinv;
      float wd = __expf(-0.5f * td * td);
      uint4 v;
      v.x = pk2(wd * wp[0], wd * wp[1]);
      v.y = pk2(wd * wp[2], wd * wp[3]);
      v.z = pk2(wd * wp[4], wd * wp[5]);
      v.w = pk2(wd * wp[6], wd * wp[7]);
      *(uint4*)(wrow + d * 4) = v;
    }
  }

  // ---- P0c: commit gathered x as packed bf16
  {
    unsigned* xrow = xpk + gr * XPK_R + gk * 36;
#pragma unroll
    for (int q = 0; q < 8; ++q) {
      float4 a = xreg[2 * q], b = xreg[2 * q + 1];
      uint4 v;
      v.x = pk2(a.x, a.y);
      v.y = pk2(a.z, a.w);
      v.z = pk2(b.x, b.y);
      v.w = pk2(b.z, b.w);
      *(uint4*)(xrow + q * 4) = v;
    }
  }
  __syncthreads();

  // ---- P1: normalize wb in place. thread -> (r = t&31, mp = t>>5 [u32 idx])
  {
    int r = t & 31, mp = t >> 5;
    unsigned* col = wb + r * WB_R + mp;
    unsigned v[16];
    float s0 = 0.f, s1 = 0.f;
#pragma unroll
    for (int k = 0; k < 16; ++k) {
      v[k] = col[k * 20];
      s0 += ulo(v[k]);
      s1 += uhi(v[k]);
    }
    float i0 = 1.0f / (s0 + 1e-9f);
    float i1 = 1.0f / (s1 + 1e-9f);
#pragma unroll
    for (int k = 0; k < 16; ++k)
      col[k * 20] = pk2(ulo(v[k]) * i0, uhi(v[k]) * i1);
  }
  __syncthreads();

  // ---- main: 4 m-chunks
  const int lane = t & 63;
  const int wv   = t >> 6;
  const int cg   = wv & 3;       // 64-col group
  const int half = wv >> 2;      // kk parity

  const int er  = t & 31;        // einsum row
  const int efo = (t >> 5) & 7;  // f-octet
  const int ems = t >> 8;        // m-sub (4 m each)

  f32x4_t cacc[2][4];
#pragma unroll
  for (int mt = 0; mt < 2; ++mt)
#pragma unroll
    for (int i = 0; i < 4; ++i)
      cacc[mt][i] = (f32x4_t){0.f, 0.f, 0.f, 0.f};

  uint4 bpre[2][4];

  for (int d = 0; d < 4; ++d) {
    // B prefetch for j=0,1 of this chunk — in flight during whole einsum
#pragma unroll
    for (int s = 0; s < 2; ++s) {
      const uint4* pb = Bws + (size_t)(d * 16 + 2 * s + half) * 1024
                            + (cg * 4) * 64 + lane;
#pragma unroll
      for (int i = 0; i < 4; ++i) bpre[s][i] = pb[i * 64];
    }

    // einsum: 4 m x 8 f per thread
    f32x2_t acc[4][4];
#pragma unroll
    for (int mi = 0; mi < 4; ++mi)
#pragma unroll
      for (int fj = 0; fj < 4; ++fj) acc[mi][fj] = (f32x2_t){0.f, 0.f};

    const unsigned* xr_ = xpk + er * XPK_R + efo * 4;
    const unsigned* wr_ = wb + er * WB_R + d * 4 + ems * 2;

#pragma unroll 8
    for (int k = 0; k < 16; ++k) {
      uint4 xu = *(const uint4*)(xr_ + k * 36);
      unsigned w0 = wr_[k * 20], w1 = wr_[k * 20 + 1];
      float wm[4] = {ulo(w0), uhi(w0), ulo(w1), uhi(w1)};
      f32x2_t xv[4];
      xv[0] = (f32x2_t){ulo(xu.x), uhi(xu.x)};
      xv[1] = (f32x2_t){ulo(xu.y), uhi(xu.y)};
      xv[2] = (f32x2_t){ulo(xu.z), uhi(xu.z)};
      xv[3] = (f32x2_t){ulo(xu.w), uhi(xu.w)};
#pragma unroll
      for (int mi = 0; mi < 4; ++mi) {
        f32x2_t wmm = (f32x2_t){wm[mi], wm[mi]};
#pragma unroll
        for (int fj = 0; fj < 4; ++fj)
          acc[mi][fj] += wmm * xv[fj];
      }
    }

    // write A-fragment chunk: lane (er&15)+((efo&3)<<4), kkl = m_l*2+(efo>>2)
    {
      const int mt_   = er >> 4;
      const int lane_ = (er & 15) + ((efo & 3) << 4);
      const int kb    = efo >> 2;
#pragma unroll
      for (int mi = 0; mi < 4; ++mi) {
        int m_l = ems * 4 + mi;
        int kkl = m_l * 2 + kb;
        uint4 v;
        v.x = pk2(acc[mi][0][0], acc[mi][0][1]);
        v.y = pk2(acc[mi][1][0], acc[mi][1][1]);
        v.z = pk2(acc[mi][2][0], acc[mi][2][1]);
        v.w = pk2(acc[mi][3][0], acc[mi][3][1]);
        ac[(mt_ * 16 + kkl) * 64 + lane_] = v;
      }
    }
    __syncthreads();

    // MFMA over this chunk: kkl = 2j + half
#pragma unroll
    for (int j = 0; j < 8; ++j) {
      const int s   = j & 1;
      const int kkl = 2 * j + half;
      uint4 A0 = ac[kkl * 64 + lane];
      uint4 A1 = ac[(16 + kkl) * 64 + lane];
      uint4 bcur[4];
#pragma unroll
      for (int i = 0; i < 4; ++i) bcur[i] = bpre[s][i];
      if (j < 6) {
        const uint4* pb = Bws + (size_t)(d * 16 + 2 * (j + 2) + half) * 1024
                              + (cg * 4) * 64 + lane;
#pragma unroll
        for (int i = 0; i < 4; ++i) bpre[s][i] = pb[i * 64];
      }
      bf16x8_t a0 = __builtin_bit_cast(bf16x8_t, A0);
      bf16x8_t a1 = __builtin_bit_cast(bf16x8_t, A1);
#pragma unroll
      for (int i = 0; i < 4; ++i) {
        bf16x8_t b = __builtin_bit_cast(bf16x8_t, bcur[i]);
        cacc[0][i] = __builtin_amdgcn_mfma_f32_16x16x32_bf16(a0, b, cacc[0][i], 0, 0, 0);
        cacc[1][i] = __builtin_amdgcn_mfma_f32_16x16x32_bf16(a1, b, cacc[1][i], 0, 0, 0);
      }
    }
    __syncthreads();
  }

  // ---- Epilogue: cross-half reduction via LDS (xpk region dead -> reuse)
  float* red = (float*)(smem + XPK_OFF);   // [cg][32][68] f32 = 34816 B
  const int lrow = (lane >> 4) * 4;
  const int lcol = lane & 15;

  if (half == 0) {
#pragma unroll
    for (int mt = 0; mt < 2; ++mt)
#pragma unroll
      for (int i = 0; i < 4; ++i)
#pragma unroll
        for (int reg = 0; reg < 4; ++reg)
          red[(cg * 32 + mt * 16 + lrow + reg) * 68 + i * 16 + lcol] =
              cacc[mt][i][reg];
  }
  __syncthreads();
  if (half == 1) {
#pragma unroll
    for (int mt = 0; mt < 2; ++mt)
#pragma unroll
      for (int i = 0; i < 4; ++i)
#pragma unroll
        for (int reg = 0; reg < 4; ++reg) {
          int row = mt * 16 + lrow + reg;
          int col = i * 16 + lcol;
          float v = red[(cg * 32 + row) * 68 + col] + cacc[mt][i][reg];
          out[(n0 + row) * OUT_D + cg * 64 + col] = v;
        }
  }
}

// ===========================================================================
extern "C" void kernel_launch(void* const* d_in, const int* in_sizes, int n_in,
                              void* d_out, int out_size, void* d_ws, size_t ws_size,
                              hipStream_t stream) {
  const float* x      = (const float*)d_in[0];
  const float* dd     = (const float*)d_in[1];
  const float* dp     = (const float*)d_in[2];
  const float* dists  = (const float*)d_in[3];
  const float* sigma  = (const float*)d_in[4];
  const float* kappa  = (const float*)d_in[5];
  const float* phi    = (const float*)d_in[6];
  const float* W      = (const float*)d_in[7];
  const int*   nh     = (const int*)d_in[8];
  float*       out    = (float*)d_out;

  uint4* Bws = (uint4*)d_ws;                 // 1 MB of B-fragments

  pack_B_kernel<<<64, 256, 0, stream>>>(W, Bws);

  hipFuncSetAttribute((const void*)fused_kernel,
                      hipFuncAttributeMaxDynamicSharedMemorySize, LDS_TOT);
  fused_kernel<<<N_OUTP / 32, 512, LDS_TOT, stream>>>(
      x, dd, dp, dists, sigma, kappa, phi, Bws, nh, out);
}